// Round 1
// baseline (5695.279 us; speedup 1.0000x reference)
//
#include <hip/hip_runtime.h>
#include <stdint.h>

#define Kn 64
#define En 256
#define Bn 512
#define Hn 512
#define Dn 128
#define NT 256
#define HP 256          // column-pairs per row (Hn/2)
#define DT_C 0.05f

// ws layout (bytes):
//   [0, 131072)        pos  (int, Kn*Bn)  : pos[k*Bn+b] = e or -1
//   [131072, 131080)   acc  (float x2)    : loss, tot_m
//   [131584, ...)      packed bf16 weights (uint16), read as uint32 pairs
// pair offsets (uint32 units):
//   W1 0, W2 131072, Wp1 262144, Wp2 393216, Wi 425984, Wf 589824, Wo 753664, Wc 917504

__device__ __forceinline__ float bflo(uint32_t w){ return __uint_as_float(w << 16); }
__device__ __forceinline__ float bfhi(uint32_t w){ return __uint_as_float(w & 0xffff0000u); }
__device__ __forceinline__ float sigm(float x){ return 1.0f/(1.0f + __expf(-x)); }

__global__ void k_init(int* __restrict__ pos, float* __restrict__ acc){
  int i = blockIdx.x*blockDim.x + threadIdx.x;
  if (i < Kn*Bn) pos[i] = -1;
  if (i < 2) acc[i] = 0.0f;
}

__global__ void k_scatter(const int* __restrict__ bidx, int* __restrict__ pos){
  int i = blockIdx.x*blockDim.x + threadIdx.x;
  if (i < Kn*En){
    int k = i >> 8;           // En = 256
    int e = i & (En-1);
    pos[(k << 9) | bidx[i]] = e;   // Bn = 512
  }
}

__global__ void k_cvt(const float* __restrict__ src, uint16_t* __restrict__ dst, int n){
  int i = blockIdx.x*blockDim.x + threadIdx.x;
  if (i < n){
    uint32_t u = __float_as_uint(src[i]);
    uint32_t r = (u + 0x7fffu + ((u >> 16) & 1u)) >> 16;  // round-to-nearest-even
    dst[i] = (uint16_t)r;
  }
}

__global__ __launch_bounds__(NT) void k_main(
  const float* __restrict__ X, const float* __restrict__ Mm,
  const int* __restrict__ pos, const uint32_t* __restrict__ Wb,
  const float* __restrict__ bi_, const float* __restrict__ bf_,
  const float* __restrict__ bo_, const float* __restrict__ bc_,
  const float* __restrict__ b1_, const float* __restrict__ b2_,
  const float* __restrict__ bp1_, const float* __restrict__ bp2_,
  float* __restrict__ acc)
{
  const uint32_t* __restrict__ W1  = Wb;
  const uint32_t* __restrict__ W2  = Wb + 131072;
  const uint32_t* __restrict__ Wp1 = Wb + 262144;
  const uint32_t* __restrict__ Wp2 = Wb + 393216;
  const uint32_t* __restrict__ Wi  = Wb + 425984;
  const uint32_t* __restrict__ Wf  = Wb + 589824;
  const uint32_t* __restrict__ Wo  = Wb + 753664;
  const uint32_t* __restrict__ Wc  = Wb + 917504;

  const int b   = blockIdx.x;   // sample
  const int tid = threadIdx.x;
  const int j0  = tid*2, j1 = j0+1;   // this thread owns columns j0,j1

  __shared__ float sh_h[Hn];
  __shared__ float sh_c[Hn];
  __shared__ float sh_t[Hn];
  __shared__ float sh_x[Dn];
  __shared__ float red[8];

  sh_h[j0]=0.f; sh_h[j1]=0.f; sh_c[j0]=0.f; sh_c[j1]=0.f;

  // hoist biases (constant across events)
  const float vb1_0=b1_[j0],  vb1_1=b1_[j1];
  const float vb2_0=b2_[j0],  vb2_1=b2_[j1];
  const float vp1_0=bp1_[j0], vp1_1=bp1_[j1];
  const float vi0=bi_[j0], vi1=bi_[j1];
  const float vf0=bf_[j0], vf1=bf_[j1];
  const float vo0=bo_[j0], vo1=bo_[j1];
  const float vc0=bc_[j0], vc1=bc_[j1];
  float vp2_0=0.f, vp2_1=0.f;
  if (tid < Dn/2){ vp2_0=bp2_[j0]; vp2_1=bp2_[j1]; }

  float loss_loc=0.f, m_loc=0.f;

  for (int k=0;k<Kn;k++){
    // ---- two Euler steps on full h ----
    for (int s=0;s<2;s++){
      __syncthreads();                      // sh_h stable; old sh_t readers done
      float a0=vb1_0, a1=vb1_1;
      #pragma unroll 16
      for (int kk=0;kk<Hn;kk++){
        float hv = sh_h[kk];
        uint32_t w = W1[kk*HP + tid];
        a0 = fmaf(hv, bflo(w), a0);
        a1 = fmaf(hv, bfhi(w), a1);
      }
      sh_t[j0]=tanhf(a0); sh_t[j1]=tanhf(a1);
      __syncthreads();                      // sh_t complete
      a0=vb2_0; a1=vb2_1;
      #pragma unroll 16
      for (int kk=0;kk<Hn;kk++){
        float tv = sh_t[kk];
        uint32_t w = W2[kk*HP + tid];
        a0 = fmaf(tv, bflo(w), a0);
        a1 = fmaf(tv, bfhi(w), a1);
      }
      sh_h[j0] += DT_C*a0;                  // owner-only columns, safe
      sh_h[j1] += DT_C*a1;
    }
    __syncthreads();                        // h updates visible to all

    const int e = pos[(k<<9) + b];
    if (e >= 0){
      // stage X row
      if (tid < Dn) sh_x[tid] = X[((size_t)(k*En+e))*Dn + tid];
      // p_model layer 1: relu(h@Wp1+bp1) -> sh_t
      float a0=vp1_0, a1=vp1_1;
      #pragma unroll 16
      for (int kk=0;kk<Hn;kk++){
        float hv = sh_h[kk];
        uint32_t w = Wp1[kk*HP + tid];
        a0 = fmaf(hv, bflo(w), a0);
        a1 = fmaf(hv, bfhi(w), a1);
      }
      sh_t[j0]=fmaxf(a0,0.f); sh_t[j1]=fmaxf(a1,0.f);
      __syncthreads();                      // sh_t, sh_x complete

      // p_model layer 2 + loss (threads 0..63 cover D=128 as pairs)
      if (tid < Dn/2){
        float p0=vp2_0, p1=vp2_1;
        #pragma unroll 16
        for (int kk=0;kk<Hn;kk++){
          float tv = sh_t[kk];
          uint32_t w = Wp2[kk*(Dn/2) + tid];
          p0 = fmaf(tv, bflo(w), p0);
          p1 = fmaf(tv, bfhi(w), p1);
        }
        const float2* Mv = (const float2*)(Mm + ((size_t)(k*En+e))*Dn);
        float2 mo = Mv[tid];
        float2 xo = *reinterpret_cast<const float2*>(&sh_x[j0]);
        loss_loc += fabsf(xo.x-p0)*mo.x + fabsf(xo.y-p1)*mo.y;
        m_loc += mo.x + mo.y;
      }

      // LSTM gates (skip at last event: update is dead w.r.t. loss)
      if (k < Kn-1){
        float ai0=vi0, ai1=vi1, af0=vf0, af1=vf1;
        float ao0=vo0, ao1=vo1, ac0=vc0, ac1=vc1;
        #pragma unroll 8
        for (int d=0; d<Dn; d++){
          float xv = sh_x[d];
          int r = d*HP + tid;
          uint32_t wi=Wi[r], wf=Wf[r], wo=Wo[r], wc=Wc[r];
          ai0=fmaf(xv,bflo(wi),ai0); ai1=fmaf(xv,bfhi(wi),ai1);
          af0=fmaf(xv,bflo(wf),af0); af1=fmaf(xv,bfhi(wf),af1);
          ao0=fmaf(xv,bflo(wo),ao0); ao1=fmaf(xv,bfhi(wo),ao1);
          ac0=fmaf(xv,bflo(wc),ac0); ac1=fmaf(xv,bfhi(wc),ac1);
        }
        #pragma unroll 8
        for (int kk=0;kk<Hn;kk++){
          float hv = sh_h[kk];
          int r = (Dn+kk)*HP + tid;
          uint32_t wi=Wi[r], wf=Wf[r], wo=Wo[r], wc=Wc[r];
          ai0=fmaf(hv,bflo(wi),ai0); ai1=fmaf(hv,bfhi(wi),ai1);
          af0=fmaf(hv,bflo(wf),af0); af1=fmaf(hv,bfhi(wf),af1);
          ao0=fmaf(hv,bflo(wo),ao0); ao1=fmaf(hv,bfhi(wo),ao1);
          ac0=fmaf(hv,bflo(wc),ac0); ac1=fmaf(hv,bfhi(wc),ac1);
        }
        float ig0=sigm(ai0), fg0=sigm(af0), og0=sigm(ao0), ct0=tanhf(ac0);
        float ig1=sigm(ai1), fg1=sigm(af1), og1=sigm(ao1), ct1=tanhf(ac1);
        float cn0 = fg0*sh_c[j0] + ig0*ct0;
        float cn1 = fg1*sh_c[j1] + ig1*ct1;
        float hn0 = og0*tanhf(cn0);
        float hn1 = og1*tanhf(cn1);
        __syncthreads();                    // all gate-dot reads of sh_h done
        sh_h[j0]=hn0; sh_h[j1]=hn1;
        sh_c[j0]=cn0; sh_c[j1]=cn1;
      }
    }
  }

  // block reduction -> global atomics
  #pragma unroll
  for (int off=32; off>0; off>>=1){
    loss_loc += __shfl_down(loss_loc, off);
    m_loc    += __shfl_down(m_loc, off);
  }
  const int wid = tid >> 6, lane = tid & 63;
  if (lane==0){ red[wid*2]=loss_loc; red[wid*2+1]=m_loc; }
  __syncthreads();
  if (tid==0){
    atomicAdd(acc+0, red[0]+red[2]+red[4]+red[6]);
    atomicAdd(acc+1, red[1]+red[3]+red[5]+red[7]);
  }
}

__global__ void k_fin(const float* __restrict__ acc, float* __restrict__ out){
  if (threadIdx.x == 0){
    out[0] = acc[0];
    out[1] = acc[0]/acc[1];
  }
}

extern "C" void kernel_launch(void* const* d_in, const int* in_sizes, int n_in,
                              void* d_out, int out_size, void* d_ws, size_t ws_size,
                              hipStream_t stream)
{
  const float* X   = (const float*)d_in[0];
  const float* Mm  = (const float*)d_in[1];
  const int*  bidx = (const int*)d_in[2];
  // d_in[3] = sample_idx (unused, it's arange(B))
  const float* Wi  = (const float*)d_in[4];
  const float* bi  = (const float*)d_in[5];
  const float* Wf  = (const float*)d_in[6];
  const float* bff = (const float*)d_in[7];
  const float* Wo  = (const float*)d_in[8];
  const float* bo  = (const float*)d_in[9];
  const float* Wc  = (const float*)d_in[10];
  const float* bc  = (const float*)d_in[11];
  const float* W1  = (const float*)d_in[12];
  const float* b1  = (const float*)d_in[13];
  const float* W2  = (const float*)d_in[14];
  const float* b2  = (const float*)d_in[15];
  const float* Wp1 = (const float*)d_in[16];
  const float* bp1 = (const float*)d_in[17];
  const float* Wp2 = (const float*)d_in[18];
  const float* bp2 = (const float*)d_in[19];

  char* ws = (char*)d_ws;
  int*      pos  = (int*)ws;
  float*    acc  = (float*)(ws + 131072);
  uint16_t* wb16 = (uint16_t*)(ws + 131584);
  uint32_t* wb32 = (uint32_t*)(ws + 131584);

  k_init   <<<(Kn*Bn + NT-1)/NT, NT, 0, stream>>>(pos, acc);
  k_scatter<<<(Kn*En + NT-1)/NT, NT, 0, stream>>>(bidx, pos);

  // convert weights to packed bf16 (pair offsets in uint32 units -> *2 for uint16)
  {
    struct { const float* s; size_t off; int n; } cv[8] = {
      { W1,       0, Hn*Hn },
      { W2,  131072, Hn*Hn },
      { Wp1, 262144, Hn*Hn },
      { Wp2, 393216, Hn*Dn },
      { Wi,  425984, (Dn+Hn)*Hn },
      { Wf,  589824, (Dn+Hn)*Hn },
      { Wo,  753664, (Dn+Hn)*Hn },
      { Wc,  917504, (Dn+Hn)*Hn },
    };
    for (int i=0;i<8;i++)
      k_cvt<<<(cv[i].n + NT-1)/NT, NT, 0, stream>>>(cv[i].s, wb16 + cv[i].off*2, cv[i].n);
  }

  k_main<<<Bn, NT, 0, stream>>>(X, Mm, pos, wb32,
                                bi, bff, bo, bc, b1, b2, bp1, bp2, acc);
  k_fin<<<1, 64, 0, stream>>>(acc, (float*)d_out);
}